// Round 1
// baseline (1920.038 us; speedup 1.0000x reference)
//
#include <hip/hip_runtime.h>

// GCN forward, MI355X. Dead MLP/adj branch skipped (unused in reference output).
// Pipeline: deg -> dinv -> [gemm+scale -> atomic scatter -> bias+relu] x2 -> small gemm.

#define NNODE 16384
#define NEDGE 524288
#define DIM   128

__global__ __launch_bounds__(256) void k_deg_init(float* __restrict__ deg) {
    int i = blockIdx.x * 256 + threadIdx.x;
    deg[i] = 1.0f;  // self-loop contributes 1 to every node's degree
}

__global__ __launch_bounds__(256) void k_deg_count(const int* __restrict__ col,
                                                   float* __restrict__ deg) {
    int e = blockIdx.x * 256 + threadIdx.x;
    atomicAdd(&deg[col[e] & (NNODE - 1)], 1.0f);
}

__global__ __launch_bounds__(256) void k_dinv(float* __restrict__ deg) {
    int i = blockIdx.x * 256 + threadIdx.x;
    deg[i] = rsqrtf(deg[i]);  // deg >= 1 always
}

// lin[r] = (A[r] @ W_tile) * dinv[r]; also writes agg[r] = lin[r] (self-loop init).
// Tile: 64 rows x 64 cols, 256 threads, 4x4 micro-tile per thread.
// A staged transposed in LDS (stride 68 -> conflict-free-ish, float4-aligned);
// W read direct from global (64KB, L1/L2 resident across blocks).
__global__ __launch_bounds__(256) void k_gemm_scale(
    const float* __restrict__ A, const float* __restrict__ W,
    const float* __restrict__ dinv,
    float* __restrict__ lin, float* __restrict__ agg)
{
    __shared__ float As[128][68];  // [k][row], 34816 B
    const int tid  = threadIdx.x;
    const int row0 = blockIdx.x * 64;
    const int col0 = blockIdx.y * 64;

    // stage A tile transposed: 64 rows x 128 k = 8192 elems, 32/thread, coalesced global reads
    #pragma unroll
    for (int it = 0; it < 32; ++it) {
        int idx = it * 256 + tid;
        int r = idx >> 7, k = idx & 127;
        As[k][r] = A[(row0 + r) * DIM + k];
    }
    __syncthreads();

    const int tx = tid & 15, ty = tid >> 4;
    float acc[4][4] = {{0.f}};

    #pragma unroll 8
    for (int k = 0; k < 128; ++k) {
        float4 a = *(const float4*)&As[k][ty * 4];
        float4 w = *(const float4*)&W[k * DIM + col0 + tx * 4];
        acc[0][0] += a.x * w.x; acc[0][1] += a.x * w.y; acc[0][2] += a.x * w.z; acc[0][3] += a.x * w.w;
        acc[1][0] += a.y * w.x; acc[1][1] += a.y * w.y; acc[1][2] += a.y * w.z; acc[1][3] += a.y * w.w;
        acc[2][0] += a.z * w.x; acc[2][1] += a.z * w.y; acc[2][2] += a.z * w.z; acc[2][3] += a.z * w.w;
        acc[3][0] += a.w * w.x; acc[3][1] += a.w * w.y; acc[3][2] += a.w * w.z; acc[3][3] += a.w * w.w;
    }

    #pragma unroll
    for (int i = 0; i < 4; ++i) {
        int r = row0 + ty * 4 + i;
        float s = dinv[r];
        float4 v = make_float4(acc[i][0] * s, acc[i][1] * s, acc[i][2] * s, acc[i][3] * s);
        *(float4*)&lin[r * DIM + col0 + tx * 4] = v;
        *(float4*)&agg[r * DIM + col0 + tx * 4] = v;  // self-loop init
    }
}

// agg[c] += lin_scaled[r] over all edges. 32 lanes/edge, float4 read, 4 scalar atomics.
__global__ __launch_bounds__(256) void k_scatter(
    const int* __restrict__ erow, const int* __restrict__ ecol,
    const float* __restrict__ lin, float* __restrict__ agg)
{
    int t = blockIdx.x * 256 + threadIdx.x;
    int e = t >> 5;           // 8 edges per block, grid exact
    int q = t & 31;
    int r = erow[e] & (NNODE - 1);
    int c = ecol[e] & (NNODE - 1);
    float4 v = *(const float4*)&lin[r * DIM + q * 4];
    float* dst = &agg[c * DIM + q * 4];
    atomicAdd(dst + 0, v.x);
    atomicAdd(dst + 1, v.y);
    atomicAdd(dst + 2, v.z);
    atomicAdd(dst + 3, v.w);
}

// out[i] = relu(agg[i] * dinv[i] + b)
__global__ __launch_bounds__(256) void k_post(
    const float* __restrict__ agg, const float* __restrict__ dinv,
    const float* __restrict__ b, float* __restrict__ out)
{
    int t = blockIdx.x * 256 + threadIdx.x;
    int i = t >> 5, q = t & 31;
    float s = dinv[i];
    float4 v  = *(const float4*)&agg[i * DIM + q * 4];
    float4 bb = *(const float4*)&b[q * 4];
    v.x = fmaxf(fmaf(v.x, s, bb.x), 0.f);
    v.y = fmaxf(fmaf(v.y, s, bb.y), 0.f);
    v.z = fmaxf(fmaf(v.z, s, bb.z), 0.f);
    v.w = fmaxf(fmaf(v.w, s, bb.w), 0.f);
    *(float4*)&out[i * DIM + q * 4] = v;
}

// out[16384,10] = x @ W_c + b_c ; one thread per output element
__global__ __launch_bounds__(256) void k_final(
    const float* __restrict__ x, const float* __restrict__ Wc,
    const float* __restrict__ bc, float* __restrict__ out)
{
    __shared__ float Ws[DIM * 10];
    __shared__ float bs[10];
    int tid = threadIdx.x;
    for (int idx = tid; idx < DIM * 10; idx += 256) Ws[idx] = Wc[idx];
    if (tid < 10) bs[tid] = bc[tid];
    __syncthreads();
    int g = blockIdx.x * 256 + tid;     // grid exact: 16384*10/256 = 640
    int row = g / 10, j = g - row * 10;
    const float* xr = &x[row * DIM];
    float a = 0.f;
    #pragma unroll 8
    for (int k = 0; k < DIM; ++k) a = fmaf(xr[k], Ws[k * 10 + j], a);
    out[g] = a + bs[j];
}

extern "C" void kernel_launch(void* const* d_in, const int* in_sizes, int n_in,
                              void* d_out, int out_size, void* d_ws, size_t ws_size,
                              hipStream_t stream)
{
    const float* fts  = (const float*)d_in[0];
    const int*   erow = (const int*)d_in[1];
    const int*   ecol = erow + NEDGE;
    const float* W_g1 = (const float*)d_in[6];
    const float* b_g1 = (const float*)d_in[7];
    const float* W_g2 = (const float*)d_in[8];
    const float* b_g2 = (const float*)d_in[9];
    const float* W_c  = (const float*)d_in[10];
    const float* b_c  = (const float*)d_in[11];

    float* out  = (float*)d_out;          // [16384,10] flat first
    float* xout = out + NNODE * 10;       // [16384,128] second tuple element

    float* deg  = (float*)d_ws;           // 16384 (becomes dinv in-place)
    float* bufA = deg + NNODE;            // 16384*128
    float* bufB = bufA + NNODE * DIM;     // 16384*128
    float* bufC = bufB + NNODE * DIM;     // 16384*128

    k_deg_init<<<NNODE / 256, 256, 0, stream>>>(deg);
    k_deg_count<<<NEDGE / 256, 256, 0, stream>>>(ecol, deg);
    k_dinv<<<NNODE / 256, 256, 0, stream>>>(deg);

    // conv1: lin1 -> bufA, agg -> bufB, h1 -> bufA (overwrite lin1 after scatter)
    k_gemm_scale<<<dim3(NNODE / 64, 2), 256, 0, stream>>>(fts, W_g1, deg, bufA, bufB);
    k_scatter<<<NEDGE / 8, 256, 0, stream>>>(erow, ecol, bufA, bufB);
    k_post<<<NNODE * 32 / 256, 256, 0, stream>>>(bufB, deg, b_g1, bufA);

    // conv2: lin2 -> bufC, agg -> bufB, x -> d_out x-region
    k_gemm_scale<<<dim3(NNODE / 64, 2), 256, 0, stream>>>(bufA, W_g2, deg, bufC, bufB);
    k_scatter<<<NEDGE / 8, 256, 0, stream>>>(erow, ecol, bufC, bufB);
    k_post<<<NNODE * 32 / 256, 256, 0, stream>>>(bufB, deg, b_g2, xout);

    k_final<<<NNODE * 10 / 256, 256, 0, stream>>>(xout, W_c, b_c, out);
}

// Round 2
// 268.046 us; speedup vs baseline: 7.1631x; 7.1631x over previous
//
#include <hip/hip_runtime.h>

// GCN forward, MI355X. Dead MLP/adj branch skipped (unused in reference output).
// R2: atomic scatter (2x880us) replaced by CSR-by-col build + gather (zero fp32 atomics).

#define NNODE 16384
#define NEDGE 524288
#define DIM   128

__global__ __launch_bounds__(256) void k_zero(int* __restrict__ p) {
    p[blockIdx.x * 256 + threadIdx.x] = 0;
}

__global__ __launch_bounds__(256) void k_count(const int* __restrict__ ecol,
                                               int* __restrict__ cnt) {
    int e = blockIdx.x * 256 + threadIdx.x;
    atomicAdd(&cnt[ecol[e] & (NNODE - 1)], 1);
}

// Single-block: exclusive scan of 16384 counts -> rowptr & fill-cursor; dinv = rsqrt(cnt+1).
__global__ __launch_bounds__(256) void k_scan(const int* __restrict__ cnt,
                                              int* __restrict__ rowptr,
                                              int* __restrict__ cursor,
                                              float* __restrict__ dinv) {
    __shared__ int part[256];
    const int tid = threadIdx.x;
    const int base = tid * 64;
    int s = 0;
    for (int i = 0; i < 64; ++i) s += cnt[base + i];
    part[tid] = s;
    __syncthreads();
    // Hillis-Steele inclusive scan over 256 partials
    for (int off = 1; off < 256; off <<= 1) {
        int v = part[tid];
        int add = (tid >= off) ? part[tid - off] : 0;
        __syncthreads();
        part[tid] = v + add;
        __syncthreads();
    }
    int off = part[tid] - s;  // exclusive offset for this thread's 64 nodes
    for (int i = 0; i < 64; ++i) {
        int c = cnt[base + i];
        rowptr[base + i] = off;
        cursor[base + i] = off;
        dinv[base + i]   = rsqrtf((float)(c + 1));  // +1 self-loop
        off += c;
    }
    if (tid == 255) rowptr[NNODE] = off;
}

__global__ __launch_bounds__(256) void k_fill(const int* __restrict__ erow,
                                              const int* __restrict__ ecol,
                                              int* __restrict__ cursor,
                                              int* __restrict__ nbr) {
    int e = blockIdx.x * 256 + threadIdx.x;
    int r = erow[e] & (NNODE - 1);
    int c = ecol[e] & (NNODE - 1);
    int pos = atomicAdd(&cursor[c], 1);
    nbr[pos] = r;
}

// lin[r] = (A[r] @ W_tile) * dinv[r]. 64x64 tile, 256 threads, 4x4 micro-tile.
__global__ __launch_bounds__(256) void k_gemm_scale(
    const float* __restrict__ A, const float* __restrict__ W,
    const float* __restrict__ dinv, float* __restrict__ lin)
{
    __shared__ float As[128][68];  // [k][row]
    const int tid  = threadIdx.x;
    const int row0 = blockIdx.x * 64;
    const int col0 = blockIdx.y * 64;

    #pragma unroll
    for (int it = 0; it < 32; ++it) {
        int idx = it * 256 + tid;
        int r = idx >> 7, k = idx & 127;
        As[k][r] = A[(row0 + r) * DIM + k];
    }
    __syncthreads();

    const int tx = tid & 15, ty = tid >> 4;
    float acc[4][4] = {{0.f}};

    #pragma unroll 8
    for (int k = 0; k < 128; ++k) {
        float4 a = *(const float4*)&As[k][ty * 4];
        float4 w = *(const float4*)&W[k * DIM + col0 + tx * 4];
        acc[0][0] += a.x * w.x; acc[0][1] += a.x * w.y; acc[0][2] += a.x * w.z; acc[0][3] += a.x * w.w;
        acc[1][0] += a.y * w.x; acc[1][1] += a.y * w.y; acc[1][2] += a.y * w.z; acc[1][3] += a.y * w.w;
        acc[2][0] += a.z * w.x; acc[2][1] += a.z * w.y; acc[2][2] += a.z * w.z; acc[2][3] += a.z * w.w;
        acc[3][0] += a.w * w.x; acc[3][1] += a.w * w.y; acc[3][2] += a.w * w.z; acc[3][3] += a.w * w.w;
    }

    #pragma unroll
    for (int i = 0; i < 4; ++i) {
        int r = row0 + ty * 4 + i;
        float s = dinv[r];
        *(float4*)&lin[r * DIM + col0 + tx * 4] =
            make_float4(acc[i][0] * s, acc[i][1] * s, acc[i][2] * s, acc[i][3] * s);
    }
}

// Per node c: out[c] = relu(dinv[c] * (lin[c] + sum_{r in N(c)} lin[r]) + b).
// 128 threads (half-block) per node, thread = channel; 4-way neighbor unroll for MLP.
__global__ __launch_bounds__(256) void k_gather(
    const int* __restrict__ rowptr, const int* __restrict__ nbr,
    const float* __restrict__ lin, const float* __restrict__ dinv,
    const float* __restrict__ bias, float* __restrict__ out)
{
    int node = blockIdx.x * 2 + (threadIdx.x >> 7);
    int d = threadIdx.x & 127;
    int beg = rowptr[node], end = rowptr[node + 1];
    float acc = lin[node * DIM + d];  // self-loop
    int i = beg;
    for (; i + 4 <= end; i += 4) {
        int r0 = nbr[i]     & (NNODE - 1);
        int r1 = nbr[i + 1] & (NNODE - 1);
        int r2 = nbr[i + 2] & (NNODE - 1);
        int r3 = nbr[i + 3] & (NNODE - 1);
        float v0 = lin[r0 * DIM + d], v1 = lin[r1 * DIM + d];
        float v2 = lin[r2 * DIM + d], v3 = lin[r3 * DIM + d];
        acc += (v0 + v1) + (v2 + v3);
    }
    for (; i < end; ++i) acc += lin[(nbr[i] & (NNODE - 1)) * DIM + d];
    out[node * DIM + d] = fmaxf(fmaf(acc, dinv[node], bias[d]), 0.f);
}

// out[16384,10] = x @ W_c + b_c
__global__ __launch_bounds__(256) void k_final(
    const float* __restrict__ x, const float* __restrict__ Wc,
    const float* __restrict__ bc, float* __restrict__ out)
{
    __shared__ float Ws[DIM * 10];
    __shared__ float bs[10];
    int tid = threadIdx.x;
    for (int idx = tid; idx < DIM * 10; idx += 256) Ws[idx] = Wc[idx];
    if (tid < 10) bs[tid] = bc[tid];
    __syncthreads();
    int g = blockIdx.x * 256 + tid;
    int row = g / 10, j = g - row * 10;
    const float* xr = &x[row * DIM];
    float a = 0.f;
    #pragma unroll 8
    for (int k = 0; k < DIM; ++k) a = fmaf(xr[k], Ws[k * 10 + j], a);
    out[g] = a + bs[j];
}

extern "C" void kernel_launch(void* const* d_in, const int* in_sizes, int n_in,
                              void* d_out, int out_size, void* d_ws, size_t ws_size,
                              hipStream_t stream)
{
    const float* fts  = (const float*)d_in[0];
    const int*   erow = (const int*)d_in[1];
    const int*   ecol = erow + NEDGE;
    const float* W_g1 = (const float*)d_in[6];
    const float* b_g1 = (const float*)d_in[7];
    const float* W_g2 = (const float*)d_in[8];
    const float* b_g2 = (const float*)d_in[9];
    const float* W_c  = (const float*)d_in[10];
    const float* b_c  = (const float*)d_in[11];

    float* out  = (float*)d_out;          // [16384,10]
    float* xout = out + NNODE * 10;       // [16384,128]

    // workspace layout (all 64B-aligned region sizes)
    float* dinv   = (float*)d_ws;                 // 16384 f32
    int*   cnt    = (int*)(dinv + NNODE);         // 16384 i32
    int*   rowptr = cnt + NNODE;                  // 16448 i32 (16385 used)
    int*   cursor = rowptr + 16448;               // 16384 i32
    int*   nbr    = cursor + NNODE;               // 524288 i32
    float* bufA   = (float*)(nbr + NEDGE);        // 16384*128 f32
    float* bufB   = bufA + NNODE * DIM;           // 16384*128 f32

    // CSR build (by destination col)
    k_zero <<<NNODE / 256, 256, 0, stream>>>(cnt);
    k_count<<<NEDGE / 256, 256, 0, stream>>>(ecol, cnt);
    k_scan <<<1, 256, 0, stream>>>(cnt, rowptr, cursor, dinv);
    k_fill <<<NEDGE / 256, 256, 0, stream>>>(erow, ecol, cursor, nbr);

    // conv1
    k_gemm_scale<<<dim3(NNODE / 64, 2), 256, 0, stream>>>(fts, W_g1, dinv, bufA);
    k_gather    <<<NNODE / 2, 256, 0, stream>>>(rowptr, nbr, bufA, dinv, b_g1, bufB);

    // conv2
    k_gemm_scale<<<dim3(NNODE / 64, 2), 256, 0, stream>>>(bufB, W_g2, dinv, bufA);
    k_gather    <<<NNODE / 2, 256, 0, stream>>>(rowptr, nbr, bufA, dinv, b_g2, xout);

    k_final<<<NNODE * 10 / 256, 256, 0, stream>>>(xout, W_c, b_c, out);
}

// Round 3
// 246.000 us; speedup vs baseline: 7.8050x; 1.0896x over previous
//
#include <hip/hip_runtime.h>

// GCN forward, MI355X. Dead MLP/adj branch skipped (unused in reference output).
// R3: wave-per-node float4 gather (2 lane-groups x 32 lanes), k_final fused into gather2.

#define NNODE 16384
#define NEDGE 524288
#define DIM   128

__global__ __launch_bounds__(256) void k_zero(int* __restrict__ p) {
    p[blockIdx.x * 256 + threadIdx.x] = 0;
}

__global__ __launch_bounds__(256) void k_count(const int* __restrict__ ecol,
                                               int* __restrict__ cnt) {
    int e = blockIdx.x * 256 + threadIdx.x;
    atomicAdd(&cnt[ecol[e] & (NNODE - 1)], 1);
}

// Single-block: exclusive scan of 16384 counts -> rowptr & fill-cursor; dinv = rsqrt(cnt+1).
__global__ __launch_bounds__(256) void k_scan(const int* __restrict__ cnt,
                                              int* __restrict__ rowptr,
                                              int* __restrict__ cursor,
                                              float* __restrict__ dinv) {
    __shared__ int part[256];
    const int tid = threadIdx.x;
    const int base = tid * 64;
    int s = 0;
    for (int i = 0; i < 64; ++i) s += cnt[base + i];
    part[tid] = s;
    __syncthreads();
    for (int off = 1; off < 256; off <<= 1) {
        int v = part[tid];
        int add = (tid >= off) ? part[tid - off] : 0;
        __syncthreads();
        part[tid] = v + add;
        __syncthreads();
    }
    int off = part[tid] - s;
    for (int i = 0; i < 64; ++i) {
        int c = cnt[base + i];
        rowptr[base + i] = off;
        cursor[base + i] = off;
        dinv[base + i]   = rsqrtf((float)(c + 1));
        off += c;
    }
    if (tid == 255) rowptr[NNODE] = off;
}

__global__ __launch_bounds__(256) void k_fill(const int* __restrict__ erow,
                                              const int* __restrict__ ecol,
                                              int* __restrict__ cursor,
                                              int* __restrict__ nbr) {
    int e = blockIdx.x * 256 + threadIdx.x;
    int r = erow[e] & (NNODE - 1);
    int c = ecol[e] & (NNODE - 1);
    int pos = atomicAdd(&cursor[c], 1);
    nbr[pos] = r;
}

// lin[r] = (A[r] @ W_tile) * dinv[r]. 64x64 tile, 256 threads, 4x4 micro-tile.
__global__ __launch_bounds__(256) void k_gemm_scale(
    const float* __restrict__ A, const float* __restrict__ W,
    const float* __restrict__ dinv, float* __restrict__ lin)
{
    __shared__ float As[128][68];  // [k][row]
    const int tid  = threadIdx.x;
    const int row0 = blockIdx.x * 64;
    const int col0 = blockIdx.y * 64;

    #pragma unroll
    for (int it = 0; it < 32; ++it) {
        int idx = it * 256 + tid;
        int r = idx >> 7, k = idx & 127;
        As[k][r] = A[(row0 + r) * DIM + k];
    }
    __syncthreads();

    const int tx = tid & 15, ty = tid >> 4;
    float acc[4][4] = {{0.f}};

    #pragma unroll 8
    for (int k = 0; k < 128; ++k) {
        float4 a = *(const float4*)&As[k][ty * 4];
        float4 w = *(const float4*)&W[k * DIM + col0 + tx * 4];
        acc[0][0] += a.x * w.x; acc[0][1] += a.x * w.y; acc[0][2] += a.x * w.z; acc[0][3] += a.x * w.w;
        acc[1][0] += a.y * w.x; acc[1][1] += a.y * w.y; acc[1][2] += a.y * w.z; acc[1][3] += a.y * w.w;
        acc[2][0] += a.z * w.x; acc[2][1] += a.z * w.y; acc[2][2] += a.z * w.z; acc[2][3] += a.z * w.w;
        acc[3][0] += a.w * w.x; acc[3][1] += a.w * w.y; acc[3][2] += a.w * w.z; acc[3][3] += a.w * w.w;
    }

    #pragma unroll
    for (int i = 0; i < 4; ++i) {
        int r = row0 + ty * 4 + i;
        float s = dinv[r];
        *(float4*)&lin[r * DIM + col0 + tx * 4] =
            make_float4(acc[i][0] * s, acc[i][1] * s, acc[i][2] * s, acc[i][3] * s);
    }
}

// Wave-per-node gather. Lane-group g (32 lanes) handles neighbors beg+g, beg+g+2, ...;
// each lane owns 4 channels (float4). Cross-group combine via shfl_xor(32).
// FINAL: additionally compute out10[node] = x @ Wc + bc (group g does cols 5g..5g+4).
template<bool FINAL>
__global__ __launch_bounds__(256) void k_gather_t(
    const int* __restrict__ rowptr, const int* __restrict__ nbr,
    const float* __restrict__ lin, const float* __restrict__ dinv,
    const float* __restrict__ bias, float* __restrict__ out,
    const float* __restrict__ Wc, const float* __restrict__ bc,
    float* __restrict__ out10)
{
    __shared__ float Ws[FINAL ? DIM * 10 : 4];
    const int tid = threadIdx.x;
    if (FINAL) {
        for (int idx = tid; idx < DIM * 10; idx += 256) Ws[idx] = Wc[idx];
        __syncthreads();
    }

    const int node = blockIdx.x * 4 + (tid >> 6);
    const int lane = tid & 63;
    const int g    = lane >> 5;
    const int c4   = lane & 31;                 // float4 channel slot: channels 4*c4..4*c4+3
    const int beg  = rowptr[node], end = rowptr[node + 1];

    float4 acc = make_float4(0.f, 0.f, 0.f, 0.f);
    if (g == 0) acc = *(const float4*)&lin[node * DIM + c4 * 4];  // self-loop

    int i = beg + g;
    for (; i + 6 < end; i += 8) {
        int r0 = nbr[i], r1 = nbr[i + 2], r2 = nbr[i + 4], r3 = nbr[i + 6];
        float4 v0 = *(const float4*)&lin[r0 * DIM + c4 * 4];
        float4 v1 = *(const float4*)&lin[r1 * DIM + c4 * 4];
        float4 v2 = *(const float4*)&lin[r2 * DIM + c4 * 4];
        float4 v3 = *(const float4*)&lin[r3 * DIM + c4 * 4];
        acc.x += (v0.x + v1.x) + (v2.x + v3.x);
        acc.y += (v0.y + v1.y) + (v2.y + v3.y);
        acc.z += (v0.z + v1.z) + (v2.z + v3.z);
        acc.w += (v0.w + v1.w) + (v2.w + v3.w);
    }
    for (; i < end; i += 2) {
        int r = nbr[i];
        float4 v = *(const float4*)&lin[r * DIM + c4 * 4];
        acc.x += v.x; acc.y += v.y; acc.z += v.z; acc.w += v.w;
    }

    acc.x += __shfl_xor(acc.x, 32);
    acc.y += __shfl_xor(acc.y, 32);
    acc.z += __shfl_xor(acc.z, 32);
    acc.w += __shfl_xor(acc.w, 32);

    const float s = dinv[node];
    const float4 bb = *(const float4*)&bias[c4 * 4];
    float4 x;
    x.x = fmaxf(fmaf(acc.x, s, bb.x), 0.f);
    x.y = fmaxf(fmaf(acc.y, s, bb.y), 0.f);
    x.z = fmaxf(fmaf(acc.z, s, bb.z), 0.f);
    x.w = fmaxf(fmaf(acc.w, s, bb.w), 0.f);
    if (g == 0) *(float4*)&out[node * DIM + c4 * 4] = x;

    if (FINAL) {
        // both groups hold full x fragment; group g computes output cols jb..jb+4
        const int jb = 5 * g;
        const float xa[4] = {x.x, x.y, x.z, x.w};
        float s0 = 0.f, s1 = 0.f, s2 = 0.f, s3 = 0.f, s4 = 0.f;
        #pragma unroll
        for (int u = 0; u < 4; ++u) {
            const float xv = xa[u];
            const float* wrow = &Ws[(c4 * 4 + u) * 10 + jb];
            s0 = fmaf(xv, wrow[0], s0);
            s1 = fmaf(xv, wrow[1], s1);
            s2 = fmaf(xv, wrow[2], s2);
            s3 = fmaf(xv, wrow[3], s3);
            s4 = fmaf(xv, wrow[4], s4);
        }
        #pragma unroll
        for (int off = 1; off < 32; off <<= 1) {
            s0 += __shfl_xor(s0, off);
            s1 += __shfl_xor(s1, off);
            s2 += __shfl_xor(s2, off);
            s3 += __shfl_xor(s3, off);
            s4 += __shfl_xor(s4, off);
        }
        if (c4 == 0) {
            float* o = &out10[node * 10 + jb];
            o[0] = s0 + bc[jb + 0];
            o[1] = s1 + bc[jb + 1];
            o[2] = s2 + bc[jb + 2];
            o[3] = s3 + bc[jb + 3];
            o[4] = s4 + bc[jb + 4];
        }
    }
}

extern "C" void kernel_launch(void* const* d_in, const int* in_sizes, int n_in,
                              void* d_out, int out_size, void* d_ws, size_t ws_size,
                              hipStream_t stream)
{
    const float* fts  = (const float*)d_in[0];
    const int*   erow = (const int*)d_in[1];
    const int*   ecol = erow + NEDGE;
    const float* W_g1 = (const float*)d_in[6];
    const float* b_g1 = (const float*)d_in[7];
    const float* W_g2 = (const float*)d_in[8];
    const float* b_g2 = (const float*)d_in[9];
    const float* W_c  = (const float*)d_in[10];
    const float* b_c  = (const float*)d_in[11];

    float* out  = (float*)d_out;          // [16384,10]
    float* xout = out + NNODE * 10;       // [16384,128]

    float* dinv   = (float*)d_ws;                 // 16384 f32
    int*   cnt    = (int*)(dinv + NNODE);         // 16384 i32
    int*   rowptr = cnt + NNODE;                  // 16448 i32 (16385 used)
    int*   cursor = rowptr + 16448;               // 16384 i32
    int*   nbr    = cursor + NNODE;               // 524288 i32
    float* bufA   = (float*)(nbr + NEDGE);        // 16384*128 f32
    float* bufB   = bufA + NNODE * DIM;           // 16384*128 f32

    // CSR build (bucketed by destination col)
    k_zero <<<NNODE / 256, 256, 0, stream>>>(cnt);
    k_count<<<NEDGE / 256, 256, 0, stream>>>(ecol, cnt);
    k_scan <<<1, 256, 0, stream>>>(cnt, rowptr, cursor, dinv);
    k_fill <<<NEDGE / 256, 256, 0, stream>>>(erow, ecol, cursor, nbr);

    // conv1
    k_gemm_scale<<<dim3(NNODE / 64, 2), 256, 0, stream>>>(fts, W_g1, dinv, bufA);
    k_gather_t<false><<<NNODE / 4, 256, 0, stream>>>(rowptr, nbr, bufA, dinv, b_g1, bufB,
                                                     nullptr, nullptr, nullptr);

    // conv2 (+ fused final 128->10 GEMM)
    k_gemm_scale<<<dim3(NNODE / 64, 2), 256, 0, stream>>>(bufB, W_g2, dinv, bufA);
    k_gather_t<true><<<NNODE / 4, 256, 0, stream>>>(rowptr, nbr, bufA, dinv, b_g2, xout,
                                                    W_c, b_c, out);
}

// Round 4
// 185.389 us; speedup vs baseline: 10.3568x; 1.3269x over previous
//
#include <hip/hip_runtime.h>

// GCN forward, MI355X. Dead MLP/adj branch skipped (unused in reference output).
// R4: bucket CSR (no count+scan kernels), bf16 lin buffer (4MB -> per-XCD-L2-resident
//     gather, half traffic), 16-lane-group uint4 gather, fused final GEMM in gather2.

#define NNODE 16384
#define NEDGE 524288
#define DIM   128
#define CAP   128   // max degree bucket; Poisson(32) => P(deg>=128) ~ e^-85

__device__ __forceinline__ float bflo(unsigned u) { return __uint_as_float(u << 16); }
__device__ __forceinline__ float bfhi(unsigned u) { return __uint_as_float(u & 0xFFFF0000u); }
__device__ __forceinline__ unsigned f2bf(float x) {            // RNE
    unsigned u = __float_as_uint(x);
    return (u + 0x7FFFu + ((u >> 16) & 1u)) >> 16;
}

__global__ __launch_bounds__(256) void k_zero(int* __restrict__ p) {
    p[blockIdx.x * 256 + threadIdx.x] = 0;
}

// bucket fill: cnt[c]++ gives slot; nbr[c*CAP+slot] = r
__global__ __launch_bounds__(256) void k_fill(const int* __restrict__ erow,
                                              const int* __restrict__ ecol,
                                              int* __restrict__ cnt,
                                              int* __restrict__ nbr) {
    int e = blockIdx.x * 256 + threadIdx.x;
    int r = erow[e] & (NNODE - 1);
    int c = ecol[e] & (NNODE - 1);
    int pos = atomicAdd(&cnt[c], 1) & (CAP - 1);
    nbr[(c << 7) + pos] = r;
}

__global__ __launch_bounds__(256) void k_dinv(const int* __restrict__ cnt,
                                              float* __restrict__ dinv) {
    int i = blockIdx.x * 256 + threadIdx.x;
    dinv[i] = rsqrtf((float)(cnt[i] + 1));   // +1 self-loop
}

// lin16[r] = bf16( (A[r] @ W) * dinv[r] ). 64x64 tile, 256 threads, 4x4 micro-tile.
__global__ __launch_bounds__(256) void k_gemm_scale(
    const float* __restrict__ A, const float* __restrict__ W,
    const float* __restrict__ dinv, unsigned short* __restrict__ lin)
{
    __shared__ float As[128][68];  // [k][row]
    const int tid  = threadIdx.x;
    const int row0 = blockIdx.x * 64;
    const int col0 = blockIdx.y * 64;

    #pragma unroll
    for (int it = 0; it < 32; ++it) {
        int idx = it * 256 + tid;
        int r = idx >> 7, k = idx & 127;
        As[k][r] = A[(row0 + r) * DIM + k];
    }
    __syncthreads();

    const int tx = tid & 15, ty = tid >> 4;
    float acc[4][4] = {{0.f}};

    #pragma unroll 8
    for (int k = 0; k < 128; ++k) {
        float4 a = *(const float4*)&As[k][ty * 4];
        float4 w = *(const float4*)&W[k * DIM + col0 + tx * 4];
        acc[0][0] += a.x * w.x; acc[0][1] += a.x * w.y; acc[0][2] += a.x * w.z; acc[0][3] += a.x * w.w;
        acc[1][0] += a.y * w.x; acc[1][1] += a.y * w.y; acc[1][2] += a.y * w.z; acc[1][3] += a.y * w.w;
        acc[2][0] += a.z * w.x; acc[2][1] += a.z * w.y; acc[2][2] += a.z * w.z; acc[2][3] += a.z * w.w;
        acc[3][0] += a.w * w.x; acc[3][1] += a.w * w.y; acc[3][2] += a.w * w.z; acc[3][3] += a.w * w.w;
    }

    #pragma unroll
    for (int i = 0; i < 4; ++i) {
        int r = row0 + ty * 4 + i;
        float s = dinv[r];
        unsigned p0 = f2bf(acc[i][0] * s) | (f2bf(acc[i][1] * s) << 16);
        unsigned p1 = f2bf(acc[i][2] * s) | (f2bf(acc[i][3] * s) << 16);
        *(uint2*)&lin[r * DIM + col0 + tx * 4] = make_uint2(p0, p1);
    }
}

// Wave-per-node gather from bf16 lin. 4 groups x 16 lanes; lane owns 8 channels (16B uint4).
// Group g takes neighbors g, g+4, ... Cross-group combine via shfl_xor(16|32).
// FINAL: also out10[node] = relu_x @ Wc + bc (grp0 -> cols 0..4, grp1 -> cols 5..9).
template<bool FINAL>
__global__ __launch_bounds__(256) void k_gather(
    const int* __restrict__ cnt, const int* __restrict__ nbr,
    const unsigned short* __restrict__ lin, const float* __restrict__ dinv,
    const float* __restrict__ bias, float* __restrict__ out,
    const float* __restrict__ Wc, const float* __restrict__ bc,
    float* __restrict__ out10)
{
    __shared__ float Ws[FINAL ? DIM * 10 : 4];
    const int tid = threadIdx.x;
    if (FINAL) {
        for (int i = tid; i < DIM * 10; i += 256) Ws[i] = Wc[i];
        __syncthreads();
    }

    const int node = blockIdx.x * 4 + (tid >> 6);
    const int lane = tid & 63;
    const int grp  = lane >> 4;          // 0..3
    const int cl   = lane & 15;          // channels 8*cl .. 8*cl+7
    const int deg  = cnt[node];
    const int nb   = node << 7;          // nbr bucket base

    float a[8] = {0.f,0.f,0.f,0.f,0.f,0.f,0.f,0.f};
    if (grp == 0) {  // self-loop
        uint4 u = *(const uint4*)&lin[(node << 7) + cl * 8];
        a[0] = bflo(u.x); a[1] = bfhi(u.x); a[2] = bflo(u.y); a[3] = bfhi(u.y);
        a[4] = bflo(u.z); a[5] = bfhi(u.z); a[6] = bflo(u.w); a[7] = bfhi(u.w);
    }

    int i = grp;
    for (; i + 4 < deg; i += 8) {        // 2 neighbors per group-iter
        int r0 = nbr[nb + i];
        int r1 = nbr[nb + i + 4];
        uint4 u0 = *(const uint4*)&lin[(r0 << 7) + cl * 8];
        uint4 u1 = *(const uint4*)&lin[(r1 << 7) + cl * 8];
        a[0] += bflo(u0.x) + bflo(u1.x);  a[1] += bfhi(u0.x) + bfhi(u1.x);
        a[2] += bflo(u0.y) + bflo(u1.y);  a[3] += bfhi(u0.y) + bfhi(u1.y);
        a[4] += bflo(u0.z) + bflo(u1.z);  a[5] += bfhi(u0.z) + bfhi(u1.z);
        a[6] += bflo(u0.w) + bflo(u1.w);  a[7] += bfhi(u0.w) + bfhi(u1.w);
    }
    for (; i < deg; i += 4) {
        int r = nbr[nb + i];
        uint4 u = *(const uint4*)&lin[(r << 7) + cl * 8];
        a[0] += bflo(u.x); a[1] += bfhi(u.x); a[2] += bflo(u.y); a[3] += bfhi(u.y);
        a[4] += bflo(u.z); a[5] += bfhi(u.z); a[6] += bflo(u.w); a[7] += bfhi(u.w);
    }

    #pragma unroll
    for (int k = 0; k < 8; ++k) {
        a[k] += __shfl_xor(a[k], 16);
        a[k] += __shfl_xor(a[k], 32);
    }

    const float s = dinv[node];
    const float4 b0 = *(const float4*)&bias[cl * 8];
    const float4 b1 = *(const float4*)&bias[cl * 8 + 4];
    a[0] = fmaxf(fmaf(a[0], s, b0.x), 0.f);
    a[1] = fmaxf(fmaf(a[1], s, b0.y), 0.f);
    a[2] = fmaxf(fmaf(a[2], s, b0.z), 0.f);
    a[3] = fmaxf(fmaf(a[3], s, b0.w), 0.f);
    a[4] = fmaxf(fmaf(a[4], s, b1.x), 0.f);
    a[5] = fmaxf(fmaf(a[5], s, b1.y), 0.f);
    a[6] = fmaxf(fmaf(a[6], s, b1.z), 0.f);
    a[7] = fmaxf(fmaf(a[7], s, b1.w), 0.f);

    // one dense 512B wave-store: grp0 writes first float4 of each 8-chunk, grp1 second
    if (grp == 0) *(float4*)&out[node * DIM + cl * 8]     = make_float4(a[0], a[1], a[2], a[3]);
    if (grp == 1) *(float4*)&out[node * DIM + cl * 8 + 4] = make_float4(a[4], a[5], a[6], a[7]);

    if (FINAL) {
        if (grp < 2) {
            const int jb = grp * 5;
            float s0 = 0.f, s1 = 0.f, s2 = 0.f, s3 = 0.f, s4 = 0.f;
            #pragma unroll
            for (int u = 0; u < 8; ++u) {
                const float xv = a[u];
                const float* wrow = &Ws[(cl * 8 + u) * 10 + jb];
                s0 = fmaf(xv, wrow[0], s0);
                s1 = fmaf(xv, wrow[1], s1);
                s2 = fmaf(xv, wrow[2], s2);
                s3 = fmaf(xv, wrow[3], s3);
                s4 = fmaf(xv, wrow[4], s4);
            }
            #pragma unroll
            for (int off = 1; off < 16; off <<= 1) {
                s0 += __shfl_xor(s0, off);
                s1 += __shfl_xor(s1, off);
                s2 += __shfl_xor(s2, off);
                s3 += __shfl_xor(s3, off);
                s4 += __shfl_xor(s4, off);
            }
            if (cl == 0) {
                float* o = &out10[node * 10 + jb];
                o[0] = s0 + bc[jb + 0];
                o[1] = s1 + bc[jb + 1];
                o[2] = s2 + bc[jb + 2];
                o[3] = s3 + bc[jb + 3];
                o[4] = s4 + bc[jb + 4];
            }
        }
    }
}

extern "C" void kernel_launch(void* const* d_in, const int* in_sizes, int n_in,
                              void* d_out, int out_size, void* d_ws, size_t ws_size,
                              hipStream_t stream)
{
    const float* fts  = (const float*)d_in[0];
    const int*   erow = (const int*)d_in[1];
    const int*   ecol = erow + NEDGE;
    const float* W_g1 = (const float*)d_in[6];
    const float* b_g1 = (const float*)d_in[7];
    const float* W_g2 = (const float*)d_in[8];
    const float* b_g2 = (const float*)d_in[9];
    const float* W_c  = (const float*)d_in[10];
    const float* b_c  = (const float*)d_in[11];

    float* out  = (float*)d_out;          // [16384,10]
    float* xout = out + NNODE * 10;       // [16384,128]

    float*          dinv  = (float*)d_ws;                    // 16384 f32
    int*            cnt   = (int*)(dinv + NNODE);            // 16384 i32
    int*            nbr   = cnt + NNODE;                     // 16384*128 i32 (8MB)
    float*          bufB  = (float*)(nbr + NNODE * CAP);     // 16384*128 f32 (8MB)
    unsigned short* lin16 = (unsigned short*)(bufB + NNODE * DIM);  // 16384*128 bf16 (4MB)

    k_zero<<<NNODE / 256, 256, 0, stream>>>(cnt);
    k_fill<<<NEDGE / 256, 256, 0, stream>>>(erow, ecol, cnt, nbr);
    k_dinv<<<NNODE / 256, 256, 0, stream>>>(cnt, dinv);

    // conv1
    k_gemm_scale<<<dim3(NNODE / 64, 2), 256, 0, stream>>>(fts, W_g1, dinv, lin16);
    k_gather<false><<<NNODE / 4, 256, 0, stream>>>(cnt, nbr, lin16, dinv, b_g1, bufB,
                                                   nullptr, nullptr, nullptr);
    // conv2 (+ fused final 128->10 GEMM)
    k_gemm_scale<<<dim3(NNODE / 64, 2), 256, 0, stream>>>(bufB, W_g2, dinv, lin16);
    k_gather<true><<<NNODE / 4, 256, 0, stream>>>(cnt, nbr, lin16, dinv, b_g2, xout,
                                                  W_c, b_c, out);
}

// Round 13
// 183.435 us; speedup vs baseline: 10.4671x; 1.0107x over previous
//
#include <hip/hip_runtime.h>

// GCN forward, MI355X. Dead MLP/adj branch skipped (unused in reference output).
// R9 (5th submit; GPU-acquisition timeouts, never benched): fix of R5/R7 correctness failure.
//     Root cause: register-page __shfl gather executed cross-lane reads under divergent
//     exec (per-group trip counts differ) -> ds_bpermute from inactive lanes is undefined.
//     Fix: direct-load gather (R4-proven), no cross-lane index traffic. Kept: ushort nbr
//     buckets, memset cnt, dinv folded into gemm epilogue, fused final GEMM. 6 dispatches.

#define NNODE 16384
#define NEDGE 524288
#define DIM   128
#define CAP   128        // bucket capacity; max in-degree ~60 for Binomial(E,1/N)
#define NMASK (NNODE - 1)

__device__ __forceinline__ float bflo(unsigned u) { return __uint_as_float(u << 16); }
__device__ __forceinline__ float bfhi(unsigned u) { return __uint_as_float(u & 0xFFFF0000u); }
__device__ __forceinline__ unsigned f2bf(float x) {            // RNE
    unsigned u = __float_as_uint(x);
    return (u + 0x7FFFu + ((u >> 16) & 1u)) >> 16;
}

// bucket fill: nbr16[c*CAP + cnt[c]++] = r
__global__ __launch_bounds__(256) void k_fill(const int* __restrict__ erow,
                                              const int* __restrict__ ecol,
                                              int* __restrict__ cnt,
                                              unsigned short* __restrict__ nbr) {
    int e = blockIdx.x * 256 + threadIdx.x;
    int r = erow[e] & NMASK;
    int c = ecol[e] & NMASK;
    int pos = atomicAdd(&cnt[c], 1) & (CAP - 1);
    nbr[(c << 7) + pos] = (unsigned short)r;
}

// lin16[r] = bf16( (A[r] @ W) * rsqrt(cnt[r]+1) ). 64x64 tile, 256 threads, 4x4 micro-tile.
__global__ __launch_bounds__(256) void k_gemm_scale(
    const float* __restrict__ A, const float* __restrict__ W,
    const int* __restrict__ cnt, unsigned short* __restrict__ lin)
{
    __shared__ float As[128][68];
    const int tid  = threadIdx.x;
    const int row0 = blockIdx.x * 64;
    const int col0 = blockIdx.y * 64;

    #pragma unroll
    for (int it = 0; it < 32; ++it) {
        int idx = it * 256 + tid;
        int r = idx >> 7, k = idx & 127;
        As[k][r] = A[(row0 + r) * DIM + k];
    }
    __syncthreads();

    const int tx = tid & 15, ty = tid >> 4;
    float acc[4][4] = {{0.f}};

    #pragma unroll 8
    for (int k = 0; k < 128; ++k) {
        float4 a = *(const float4*)&As[k][ty * 4];
        float4 w = *(const float4*)&W[k * DIM + col0 + tx * 4];
        acc[0][0] += a.x * w.x; acc[0][1] += a.x * w.y; acc[0][2] += a.x * w.z; acc[0][3] += a.x * w.w;
        acc[1][0] += a.y * w.x; acc[1][1] += a.y * w.y; acc[1][2] += a.y * w.z; acc[1][3] += a.y * w.w;
        acc[2][0] += a.z * w.x; acc[2][1] += a.z * w.y; acc[2][2] += a.z * w.z; acc[2][3] += a.z * w.w;
        acc[3][0] += a.w * w.x; acc[3][1] += a.w * w.y; acc[3][2] += a.w * w.z; acc[3][3] += a.w * w.w;
    }

    #pragma unroll
    for (int i = 0; i < 4; ++i) {
        int r = row0 + ty * 4 + i;
        float s = rsqrtf((float)(cnt[r] + 1));      // dinv, recomputed (no k_dinv kernel)
        unsigned p0 = f2bf(acc[i][0] * s) | (f2bf(acc[i][1] * s) << 16);
        unsigned p1 = f2bf(acc[i][2] * s) | (f2bf(acc[i][3] * s) << 16);
        *(uint2*)&lin[r * DIM + col0 + tx * 4] = make_uint2(p0, p1);
    }
}

// Wave-per-node gather (pre-scaled bf16 lin, pure fp32 sum). 4 groups x 16 lanes; lane owns
// 8 channels (uint4 of bf16x8). Group g handles slots j = g, g+4, ... via DIRECT nbr loads
// (bucket = 1-2 L1 lines); 4 independent ushort loads + 4 uint4 lin loads in flight.
// FINAL: also out10[node] = relu_x @ Wc + bc (grp0 -> cols 0..4, grp1 -> cols 5..9).
template<bool FINAL>
__global__ __launch_bounds__(256) void k_gather(
    const int* __restrict__ cnt, const unsigned short* __restrict__ nbr,
    const unsigned short* __restrict__ lin,
    const float* __restrict__ bias, float* __restrict__ out,
    const float* __restrict__ Wc, const float* __restrict__ bc,
    float* __restrict__ out10)
{
    __shared__ float Ws[FINAL ? DIM * 10 : 4];
    const int tid = threadIdx.x;
    if (FINAL) {
        for (int i = tid; i < DIM * 10; i += 256) Ws[i] = Wc[i];
        __syncthreads();
    }

    const int node = blockIdx.x * 4 + (tid >> 6);
    const int lane = tid & 63;
    const int grp  = lane >> 4;
    const int cl   = lane & 15;
    const int deg  = cnt[node];
    const float dn = rsqrtf((float)(deg + 1));
    const int  nb  = node << 7;

    float a[8] = {0.f,0.f,0.f,0.f,0.f,0.f,0.f,0.f};
    if (grp == 0) {  // self-loop (lin pre-scaled by dinv[node])
        uint4 u = *(const uint4*)&lin[(node << 7) + cl * 8];
        a[0] = bflo(u.x); a[1] = bfhi(u.x); a[2] = bflo(u.y); a[3] = bfhi(u.y);
        a[4] = bflo(u.z); a[5] = bfhi(u.z); a[6] = bflo(u.w); a[7] = bfhi(u.w);
    }

#define ACC1(u)                                   \
    a[0] += bflo(u.x); a[1] += bfhi(u.x);         \
    a[2] += bflo(u.y); a[3] += bfhi(u.y);         \
    a[4] += bflo(u.z); a[5] += bfhi(u.z);         \
    a[6] += bflo(u.w); a[7] += bfhi(u.w);

    int j = grp;
    for (; j + 12 < deg; j += 16) {       // 4 neighbors per group in flight
        int r0 = nbr[nb + j]      & NMASK;
        int r1 = nbr[nb + j + 4]  & NMASK;
        int r2 = nbr[nb + j + 8]  & NMASK;
        int r3 = nbr[nb + j + 12] & NMASK;
        uint4 u0 = *(const uint4*)&lin[(r0 << 7) + cl * 8];
        uint4 u1 = *(const uint4*)&lin[(r1 << 7) + cl * 8];
        uint4 u2 = *(const uint4*)&lin[(r2 << 7) + cl * 8];
        uint4 u3 = *(const uint4*)&lin[(r3 << 7) + cl * 8];
        ACC1(u0) ACC1(u1) ACC1(u2) ACC1(u3)
    }
    for (; j < deg; j += 4) {
        int r = nbr[nb + j] & NMASK;
        uint4 u = *(const uint4*)&lin[(r << 7) + cl * 8];
        ACC1(u)
    }
#undef ACC1

    // full-wave reconvergence point; all 64 lanes active for the cross-group reduce
    #pragma unroll
    for (int k = 0; k < 8; ++k) {
        a[k] += __shfl_xor(a[k], 16);
        a[k] += __shfl_xor(a[k], 32);
    }

    const float4 b0 = *(const float4*)&bias[cl * 8];
    const float4 b1 = *(const float4*)&bias[cl * 8 + 4];
    a[0] = fmaxf(fmaf(a[0], dn, b0.x), 0.f);
    a[1] = fmaxf(fmaf(a[1], dn, b0.y), 0.f);
    a[2] = fmaxf(fmaf(a[2], dn, b0.z), 0.f);
    a[3] = fmaxf(fmaf(a[3], dn, b0.w), 0.f);
    a[4] = fmaxf(fmaf(a[4], dn, b1.x), 0.f);
    a[5] = fmaxf(fmaf(a[5], dn, b1.y), 0.f);
    a[6] = fmaxf(fmaf(a[6], dn, b1.z), 0.f);
    a[7] = fmaxf(fmaf(a[7], dn, b1.w), 0.f);

    if (grp == 0) *(float4*)&out[node * DIM + cl * 8]     = make_float4(a[0], a[1], a[2], a[3]);
    if (grp == 1) *(float4*)&out[node * DIM + cl * 8 + 4] = make_float4(a[4], a[5], a[6], a[7]);

    if (FINAL) {
        if (grp < 2) {
            // shfl_xor below stays within lanes 0..31 (off<16, XOR within 16-lane group);
            // all source lanes are inside the active grp<2 half -> defined.
            const int jb = grp * 5;
            float s0 = 0.f, s1 = 0.f, s2 = 0.f, s3 = 0.f, s4 = 0.f;
            #pragma unroll
            for (int u = 0; u < 8; ++u) {
                const float xv = a[u];
                const float* wrow = &Ws[(cl * 8 + u) * 10 + jb];
                s0 = fmaf(xv, wrow[0], s0);
                s1 = fmaf(xv, wrow[1], s1);
                s2 = fmaf(xv, wrow[2], s2);
                s3 = fmaf(xv, wrow[3], s3);
                s4 = fmaf(xv, wrow[4], s4);
            }
            #pragma unroll
            for (int off = 1; off < 16; off <<= 1) {
                s0 += __shfl_xor(s0, off);
                s1 += __shfl_xor(s1, off);
                s2 += __shfl_xor(s2, off);
                s3 += __shfl_xor(s3, off);
                s4 += __shfl_xor(s4, off);
            }
            if (cl == 0) {
                float* o = &out10[node * 10 + jb];
                o[0] = s0 + bc[jb + 0];
                o[1] = s1 + bc[jb + 1];
                o[2] = s2 + bc[jb + 2];
                o[3] = s3 + bc[jb + 3];
                o[4] = s4 + bc[jb + 4];
            }
        }
    }
}

extern "C" void kernel_launch(void* const* d_in, const int* in_sizes, int n_in,
                              void* d_out, int out_size, void* d_ws, size_t ws_size,
                              hipStream_t stream)
{
    const float* fts  = (const float*)d_in[0];
    const int*   erow = (const int*)d_in[1];
    const int*   ecol = erow + NEDGE;
    const float* W_g1 = (const float*)d_in[6];
    const float* b_g1 = (const float*)d_in[7];
    const float* W_g2 = (const float*)d_in[8];
    const float* b_g2 = (const float*)d_in[9];
    const float* W_c  = (const float*)d_in[10];
    const float* b_c  = (const float*)d_in[11];

    float* out  = (float*)d_out;          // [16384,10]
    float* xout = out + NNODE * 10;       // [16384,128]

    int*            cnt   = (int*)d_ws;                       // 64 KB
    unsigned short* nbr16 = (unsigned short*)(cnt + NNODE);   // 4 MB
    unsigned short* lin16 = nbr16 + NNODE * CAP;              // 4 MB
    float*          bufB  = (float*)(lin16 + NNODE * DIM);    // 8 MB

    hipMemsetAsync(cnt, 0, NNODE * sizeof(int), stream);
    k_fill<<<NEDGE / 256, 256, 0, stream>>>(erow, ecol, cnt, nbr16);

    // conv1
    k_gemm_scale<<<dim3(NNODE / 64, 2), 256, 0, stream>>>(fts, W_g1, cnt, lin16);
    k_gather<false><<<NNODE / 4, 256, 0, stream>>>(cnt, nbr16, lin16, b_g1, bufB,
                                                   nullptr, nullptr, nullptr);
    // conv2 + fused final 128->10 GEMM
    k_gemm_scale<<<dim3(NNODE / 64, 2), 256, 0, stream>>>(bufB, W_g2, cnt, lin16);
    k_gather<true><<<NNODE / 4, 256, 0, stream>>>(cnt, nbr16, lin16, b_g2, xout,
                                                  W_c, b_c, out);
}